// Round 3
// baseline (2055.932 us; speedup 1.0000x reference)
//
#include <hip/hip_runtime.h>
#include <stdint.h>

// dims fixed by the reference
#define TT 512
#define BB 1024
#define SS 64
#define HH 128
#define TBR (TT*BB)
#define NBATCH (TT/8)

typedef __attribute__((ext_vector_type(8))) short short8;    // 8 x bf16
typedef __attribute__((ext_vector_type(4))) float floatx4;   // MFMA acc
typedef unsigned short u16;
typedef unsigned int u32;

__device__ __forceinline__ float bf2f(u16 u){union{u32 i;float f;}v;v.i=((u32)u)<<16;return v.f;}
__device__ __forceinline__ u16 f2bf(float f){union{float f;u32 i;}v;v.f=f;u32 r=v.i+0x7FFFu+((v.i>>16)&1u);return (u16)(r>>16);}

// Deterministic dtype detector. For a bf16 weight buffer, even-indexed u16s
// are real N(0,1/8) weights: biased exponent in [96,128] (|w| >= 2^-31)
// essentially always -> count == 32. For an fp32 buffer, even u16s are the
// LOW mantissa halves of floats: ~uniform bits -> P(exponent in range) ~= 0.13
// -> count ~= 4. Threshold 24 separates by >> 10 sigma. Same answer every
// call (input-dependent only), so graph capture sees identical work.
__device__ __forceinline__ bool buf_is_bf16(const u16* p) {
  int ok = 0;
#pragma unroll
  for (int i = 0; i < 32; ++i) {
    u32 v = p[2*i] & 0x7FFFu;
    u32 e = v >> 7;
    ok += (v == 0u || (e >= 96u && e <= 128u)) ? 1 : 0;
  }
  return ok >= 24;
}

// dtype-generic element access -------------------------------------------
template<bool BF> __device__ __forceinline__ float ld1(const void* p, size_t i){
  if constexpr (BF) return bf2f(((const u16*)p)[i]);
  else              return ((const float*)p)[i];
}
__device__ __forceinline__ short8 pack8(floatx4 a, floatx4 b){
  short8 r;
  r[0]=(short)f2bf(a[0]); r[1]=(short)f2bf(a[1]); r[2]=(short)f2bf(a[2]); r[3]=(short)f2bf(a[3]);
  r[4]=(short)f2bf(b[0]); r[5]=(short)f2bf(b[1]); r[6]=(short)f2bf(b[2]); r[7]=(short)f2bf(b[3]);
  return r;
}
template<bool BF> __device__ __forceinline__ short8 ld8(const void* p, size_t i){
  if constexpr (BF) return *(const short8*)((const u16*)p + i);
  else {
    const float* f = (const float*)p + i;
    return pack8(*(const floatx4*)f, *(const floatx4*)(f + 4));
  }
}
template<bool BF> __device__ __forceinline__ void st1(void* p, size_t i, float v){
  if constexpr (BF) ((u16*)p)[i] = f2bf(v);
  else              ((float*)p)[i] = v;
}

// A-fragment-ordered LDS index for v_mfma_f32_16x16x32_bf16:
// lane (m + 16q) holds A[m][ks*32 + q*8 + j]; fragment read = ds_read_b128
// at u16 offset ks*512 + lane*8.
__device__ __forceinline__ int fragidx(int m,int k){
  return ((k>>5)<<9)+((m+(((k>>3)&3)<<4))<<3)+(k&7);
}

__device__ __forceinline__ floatx4 mfma(short8 a, short8 b, floatx4 c){
  return __builtin_amdgcn_mfma_f32_16x16x32_bf16(a,b,c,0,0,0);
}

// Head finisher for one timestep. C-frag of logits: lane (n16 + 16q) holds
// logit[row 4q+r][a=n16]. Softmax over actions = 16-lane shuffle group.
template<bool BF>
__device__ __forceinline__ void head_out(
    floatx4 a, int tstep, int wv, int n16, int q,
    float bav, float bcv, const int* abuf_slot, void* __restrict__ out, int b0)
{
  if (wv == 1) {
#pragma unroll
    for (int r = 0; r < 4; ++r) {
      float l = a[r] + bav;
      float mx = l;
#pragma unroll
      for (int d = 1; d < 16; d <<= 1) mx = fmaxf(mx, __shfl_xor(mx, d, 16));
      float e = __expf(l - mx);
      float sum = e;
#pragma unroll
      for (int d = 1; d < 16; d <<= 1) sum += __shfl_xor(sum, d, 16);
      float ls = __logf(sum);
      float lp = l - mx - ls;          // log_softmax
      float p = e / sum;
      float ent = -p * lp;
#pragma unroll
      for (int d = 1; d < 16; d <<= 1) ent += __shfl_xor(ent, d, 16);
      int act = abuf_slot[4*q + r];
      float lps = __shfl(lp, act, 16);
      if (n16 == 0) {
        size_t o = ((size_t)tstep*BB + b0 + 4*q + r) * 3;
        st1<BF>(out, o,     lps);
        st1<BF>(out, o + 1, ent);
      }
    }
  } else {  // wv == 2: value; Wc lives in col 0 (n16==0 lanes)
#pragma unroll
    for (int r = 0; r < 4; ++r) {
      if (n16 == 0) {
        size_t o = ((size_t)tstep*BB + b0 + 4*q + r) * 3;
        st1<BF>(out, o + 2, a[r] + bcv);
      }
    }
  }
}

// ---------------------------------------------------------------------------
// Fully fused MLP + GRU scan + head, templated on I/O dtype. 64 blocks x 512
// threads; block owns 16 batch rows for all 512 steps. Weights in VGPRs.
// ---------------------------------------------------------------------------
template<bool BF>
__global__ __launch_bounds__(512, 2) void k_fused(
    const void* __restrict__ x, const void* __restrict__ done_, const int* __restrict__ action,
    const void* __restrict__ gstate,
    const void* __restrict__ W1, const void* __restrict__ b1,
    const void* __restrict__ W2, const void* __restrict__ b2,
    const void* __restrict__ Wih, const void* __restrict__ bih,
    const void* __restrict__ Whh, const void* __restrict__ bhh,
    const void* __restrict__ Wa, const void* __restrict__ ba,
    const void* __restrict__ Wc, const void* __restrict__ bc,
    void* __restrict__ out)
{
  if (buf_is_bf16((const u16*)W1) != BF) return;   // dtype dispatch (uniform)

  const int tid = threadIdx.x, lane = tid & 63, wv = tid >> 6;   // wv 0..7
  const int n16 = lane & 15, q = lane >> 4;
  const int b0 = blockIdx.x * 16;
  const int jj = 16*wv + n16;           // this wave's gate/gx column (0..127)

  __shared__ __align__(16) u16 xbuf[2][8][1024];   // 8 steps x A-frag(16x64)
  __shared__ __align__(16) u16 h1f[2048];          // A-frag h1 (16x128)
  __shared__ __align__(16) u16 h2f[2048];          // A-frag h2 (16x128)
  __shared__ __align__(16) u16 hfrag[2048];        // A-frag h state (16x128)
  __shared__ float hfp[16][HH + 1];                // fp32 h state (+1 anti-bank)
  __shared__ u16 dbuf[2][128];                     // done (bf16 0/1), 8 steps x 16 rows
  __shared__ int abuf[2][128];                     // action, same layout

  // ---- weights -> VGPR B-fragments -------------------------------------
  // B[k][n] tile nt: lane (n16+16q) reads W[nt*16+n16][ks*32 + q*8 .. +7]
  short8 w1f[2], w2f[4], wif[3][4], whf[3][4], scf[4];
  float b1v, b2v, bihv[3], bhv[3];
  {
    int row = wv*16 + n16;
#pragma unroll
    for (int ks = 0; ks < 2; ++ks) w1f[ks] = ld8<BF>(W1, (size_t)row*SS + ks*32 + q*8);
    b1v = ld1<BF>(b1, row);
#pragma unroll
    for (int ks = 0; ks < 4; ++ks) w2f[ks] = ld8<BF>(W2, (size_t)row*HH + ks*32 + q*8);
    b2v = ld1<BF>(b2, row);
#pragma unroll
    for (int g = 0; g < 3; ++g) {
      int grow = g*128 + jj;
#pragma unroll
      for (int ks = 0; ks < 4; ++ks) {
        wif[g][ks] = ld8<BF>(Wih, (size_t)grow*HH + ks*32 + q*8);
        whf[g][ks] = ld8<BF>(Whh, (size_t)grow*HH + ks*32 + q*8);
      }
      bihv[g] = ld1<BF>(bih, grow);
      bhv[g]  = ld1<BF>(bhh, grow);
    }
  }
  if (wv == 1) {
#pragma unroll
    for (int ks = 0; ks < 4; ++ks) scf[ks] = ld8<BF>(Wa, (size_t)n16*HH + ks*32 + q*8);
  } else if (wv == 2) {
#pragma unroll
    for (int ks = 0; ks < 4; ++ks) {
      short8 z = {0,0,0,0,0,0,0,0};
      if (n16 == 0) z = ld8<BF>(Wc, (size_t)ks*32 + q*8);
      scf[ks] = z;
    }
  } else {
#pragma unroll
    for (int ks = 0; ks < 4; ++ks) { short8 z = {0,0,0,0,0,0,0,0}; scf[ks] = z; }
  }
  const float bav = ld1<BF>(ba, n16);
  const float bcv = ld1<BF>(bc, 0);

  // ---- init h state + batch-0 staging ----------------------------------
  for (int i = tid; i < 2048; i += 512) {
    int m = i >> 7, c = i & 127;
    float v = ld1<BF>(gstate, (size_t)(b0 + m)*HH + c);
    hfp[m][c] = v;
    hfrag[fragidx(m, c)] = f2bf(v);
  }
  {
    size_t base = ((size_t)wv*BB + b0 + n16)*SS + q*8;     // steps 0..7
    *(short8*)(&xbuf[0][wv][0]   + lane*8) = ld8<BF>(x, base);
    *(short8*)(&xbuf[0][wv][512] + lane*8) = ld8<BF>(x, base + 32);
  }
  if (tid < 128) {
    int ss = tid >> 4, m = tid & 15;
    size_t idx = (size_t)ss*BB + b0 + m;
    dbuf[0][tid] = f2bf(ld1<BF>(done_, idx));   // 0/1 exact in bf16
    abuf[0][tid] = action[idx];
  }
  __syncthreads();

  // next-batch prefetch registers (raw dtype: no conversion until parked,
  // so no vmcnt wait is forced at issue time)
  short8 xr0 = {0,0,0,0,0,0,0,0}, xr1 = {0,0,0,0,0,0,0,0};  // BF path
  floatx4 fxr[4];                                           // fp32 path
  fxr[0] = fxr[1] = fxr[2] = fxr[3] = floatx4{0.f,0.f,0.f,0.f};
  u16 dreg = 0; float dregf = 0.f; int areg = 0;

  for (int t = 0; t < TT; ++t) {
    const int tb = t >> 3, s = t & 7;

    // phase 0 (batch start): issue next batch's global loads -> registers
    if (s == 0 && tb + 1 < NBATCH) {
      size_t base = ((size_t)((tb+1)*8 + wv)*BB + b0 + n16)*SS + q*8;
      if constexpr (BF) {
        xr0 = *(const short8*)((const u16*)x + base);
        xr1 = *(const short8*)((const u16*)x + base + 32);
      } else {
        const float* f = (const float*)x + base;
        fxr[0] = *(const floatx4*)f;
        fxr[1] = *(const floatx4*)(f + 4);
        fxr[2] = *(const floatx4*)(f + 32);
        fxr[3] = *(const floatx4*)(f + 36);
      }
      if (tid < 128) {
        int ss = tid >> 4, m = tid & 15;
        size_t idx = (size_t)((tb+1)*8 + ss)*BB + b0 + m;
        if constexpr (BF) dreg = ((const u16*)done_)[idx];
        else              dregf = ((const float*)done_)[idx];
        areg = action[idx];
      }
    }

    // phase 1: h_{t-1} A-fragments
    short8 haf[4];
#pragma unroll
    for (int ks = 0; ks < 4; ++ks) haf[ks] = *(const short8*)(hfrag + ks*512 + lane*8);

    // phase 2: gh = h @ W_hh^T  (wave's 3 gate tiles)
    floatx4 agh[3];
#pragma unroll
    for (int g = 0; g < 3; ++g) {
      floatx4 a = {0.f,0.f,0.f,0.f};
#pragma unroll
      for (int ks = 0; ks < 4; ++ks) a = mfma(haf[ks], whf[g][ks], a);
      agh[g] = a;
    }

    // phase 3: fused head for step t-1 (haf holds h after step t-1)
    if (t > 0 && (wv == 1 || wv == 2)) {
      floatx4 a = {0.f,0.f,0.f,0.f};
#pragma unroll
      for (int ks = 0; ks < 4; ++ks) a = mfma(haf[ks], scf[ks], a);
      int tm1 = t - 1;
      head_out<BF>(a, tm1, wv, n16, q, bav, bcv,
                   &abuf[(tm1 >> 3) & 1][(tm1 & 7)*16], out, b0);
    }

    // phase 4: MLP for step t -> gx in registers
    short8 xa0 = *(const short8*)(&xbuf[tb & 1][s][0]   + lane*8);
    short8 xa1 = *(const short8*)(&xbuf[tb & 1][s][512] + lane*8);
    floatx4 a1 = {0.f,0.f,0.f,0.f};
    a1 = mfma(xa0, w1f[0], a1);
    a1 = mfma(xa1, w1f[1], a1);
#pragma unroll
    for (int r = 0; r < 4; ++r) {
      float v = a1[r] + b1v; v = v > 0.f ? v : 0.f;
      h1f[fragidx(4*q + r, jj)] = f2bf(v);
    }
    __syncthreads();                                   // S1
    short8 h1a[4];
#pragma unroll
    for (int ks = 0; ks < 4; ++ks) h1a[ks] = *(const short8*)(h1f + ks*512 + lane*8);
    floatx4 a2 = {0.f,0.f,0.f,0.f};
#pragma unroll
    for (int ks = 0; ks < 4; ++ks) a2 = mfma(h1a[ks], w2f[ks], a2);
#pragma unroll
    for (int r = 0; r < 4; ++r) {
      float v = a2[r] + b2v; v = v > 0.f ? v : 0.f;
      h2f[fragidx(4*q + r, jj)] = f2bf(v);
    }
    __syncthreads();                                   // S2
    short8 h2a[4];
#pragma unroll
    for (int ks = 0; ks < 4; ++ks) h2a[ks] = *(const short8*)(h2f + ks*512 + lane*8);
    floatx4 agx[3];
#pragma unroll
    for (int g = 0; g < 3; ++g) {
      floatx4 a = {0.f,0.f,0.f,0.f};
#pragma unroll
      for (int ks = 0; ks < 4; ++ks) a = mfma(h2a[ks], wif[g][ks], a);
      agx[g] = a;
    }

    // phase 5: gates (fp32). Lane owns (rows 4q+r, col jj) exclusively.
#pragma unroll
    for (int r = 0; r < 4; ++r) {
      int row = 4*q + r;
      float s4 = 1.f - bf2f(dbuf[tb & 1][s*16 + row]);
      float xr = agx[0][r] + bihv[0];
      float xz = agx[1][r] + bihv[1];
      float xn = agx[2][r] + bihv[2];
      float hr = s4*agh[0][r] + bhv[0];   // done-mask: gh linear in h
      float hz = s4*agh[1][r] + bhv[1];
      float hn = s4*agh[2][r] + bhv[2];
      float rg = 1.f / (1.f + __expf(-(xr + hr)));
      float zg = 1.f / (1.f + __expf(-(xz + hz)));
      float ni = xn + rg*hn;
      float ng = 2.f / (1.f + __expf(-2.f*ni)) - 1.f;   // tanh
      float hold = hfp[row][jj] * s4;
      float hnew = (1.f - zg)*ng + zg*hold;
      hfp[row][jj] = hnew;
      hfrag[fragidx(row, jj)] = f2bf(hnew);
      if (t == TT - 1)
        st1<BF>(out, (size_t)3*TBR + (size_t)(b0 + row)*HH + jj, hnew);
    }

    // phase 5.5 (batch end): park staged next-batch data into LDS.
    if (s == 7 && tb + 1 < NBATCH) {
      short8 p0, p1;
      if constexpr (BF) { p0 = xr0; p1 = xr1; }
      else { p0 = pack8(fxr[0], fxr[1]); p1 = pack8(fxr[2], fxr[3]); }
      *(short8*)(&xbuf[(tb+1) & 1][wv][0]   + lane*8) = p0;
      *(short8*)(&xbuf[(tb+1) & 1][wv][512] + lane*8) = p1;
      if (tid < 128) {
        dbuf[(tb+1) & 1][tid] = BF ? dreg : f2bf(dregf);
        abuf[(tb+1) & 1][tid] = areg;
      }
    }
    __syncthreads();                                   // S3
  }

  // epilogue: head for t = 511 (hfrag holds h_511 after final S3)
  {
    short8 haf[4];
#pragma unroll
    for (int ks = 0; ks < 4; ++ks) haf[ks] = *(const short8*)(hfrag + ks*512 + lane*8);
    if (wv == 1 || wv == 2) {
      floatx4 a = {0.f,0.f,0.f,0.f};
#pragma unroll
      for (int ks = 0; ks < 4; ++ks) a = mfma(haf[ks], scf[ks], a);
      head_out<BF>(a, TT-1, wv, n16, q, bav, bcv,
                   &abuf[((TT-1) >> 3) & 1][((TT-1) & 7)*16], out, b0);
    }
  }
}

// ---------------------------------------------------------------------------
extern "C" void kernel_launch(void* const* d_in, const int* in_sizes, int n_in,
                              void* d_out, int out_size, void* d_ws, size_t ws_size,
                              hipStream_t stream) {
  const void* x    = d_in[0];
  const void* done = d_in[1];
  const int*  act  = (const int*)d_in[2];
  const void* gst  = d_in[3];
  const void* W1   = d_in[4];
  const void* b1   = d_in[5];
  const void* W2   = d_in[6];
  const void* b2   = d_in[7];
  const void* Wih  = d_in[8];
  const void* bih  = d_in[9];
  const void* Whh  = d_in[10];
  const void* bhh  = d_in[11];
  const void* Wa   = d_in[12];
  const void* ba   = d_in[13];
  const void* Wc   = d_in[14];
  const void* bc   = d_in[15];

  // Launch both dtype variants; each checks W1 on-device and exactly one
  // proceeds (deterministic per input buffer -> graph-capture safe).
  hipLaunchKernelGGL((k_fused<true>),  dim3(64), dim3(512), 0, stream,
                     x, done, act, gst, W1, b1, W2, b2, Wih, bih,
                     Whh, bhh, Wa, ba, Wc, bc, d_out);
  hipLaunchKernelGGL((k_fused<false>), dim3(64), dim3(512), 0, stream,
                     x, done, act, gst, W1, b1, W2, b2, Wih, bih,
                     Whh, bhh, Wa, ba, Wc, bc, d_out);
}